// Round 5
// baseline (110.196 us; speedup 1.0000x reference)
//
#include <hip/hip_runtime.h>
#include <hip/hip_bf16.h>

// TSM temporal shift + 1x1 conv (256->256) fused as bf16 MFMA GEMM.
// x: [128, 256, 28, 28] f32, w: [256, 256] f32, out: [128, 256, 28, 28] f32.
// out[n,o,p] = sum_c W[o,c] * Y_n[c,p],
//   Y_n[c,p] = x[n-1,c,p] (c<32, t>0), x[n+1,c,p] (32<=c<64, t<7), x[n,c,p] else.
//
// R5: high-TLP small-block design. 6272 blocks x 256 thr (4 waves), each block
// one 16px x 256ch tile. ~6 blocks/CU resident in independent, staggered
// phases -> memory pipe never drains (no explicit pipelining needed).
// Conversion to bf16 done once at staging (8 pk2/thread). LDS swizzle
// cc = c ^ ((p&3)<<5) puts swizzle bits on kk (loop-uniform), not g ->
// ds_read_b128 is uniform 8-accesses/bank (conflict-free); b32 writes 2-way.
// W pre-converted to bf16 once (wconv). XCD-bijective block swizzle.

#define CDIM 256
#define HWPX 784
#define FRST (CDIM * HWPX)        // floats per frame
#define TPX  16                   // pixels per tile
#define NPT  49                   // tiles per frame (49*16 = 784)
#define NWG  (NPT * 128)          // 6272, % 8 == 0
#define LROW 264                  // bf16 per LDS pixel row (528B)

using bf16x8 = __attribute__((ext_vector_type(8))) short;
using f32x4  = __attribute__((ext_vector_type(4))) float;

static __device__ __forceinline__ unsigned int pk2(float lo, float hi) {
    union { __hip_bfloat162 h; unsigned int u; } cv;
    cv.h = __float22bfloat162_rn(make_float2(lo, hi));
    return cv.u;
}

// ---- W f32 -> bf16 row-major (one-shot, 256KB read / 128KB write) ----------
__global__ void wconv(const float* __restrict__ w, unsigned short* __restrict__ wb) {
    const int i = (blockIdx.x * 256 + threadIdx.x) * 4;
    f32x4 v = *(const f32x4*)(w + i);
    *(uint2*)(wb + i) = make_uint2(pk2(v[0], v[1]), pk2(v[2], v[3]));
}

__global__ __launch_bounds__(256, 6)
void tsm_tlp(const float* __restrict__ x,
             const unsigned short* __restrict__ wb,
             float* __restrict__ out) {
    __shared__ __align__(16) unsigned short y[TPX * LROW];   // 8448 B

    // XCD-bijective swizzle: 6272 % 8 == 0 -> each XCD gets a contiguous
    // chunk of (n, pt) space; pt-neighbors (sharing 128B x-lines) co-XCD.
    const int bid = blockIdx.x;
    const int w0  = (bid & 7) * (NWG / 8) + (bid >> 3);
    const int n   = w0 / NPT;               // frame 0..127 (magic-mul)
    const int pt  = w0 - n * NPT;           // tile 0..48
    const int p0  = pt * TPX;
    const int tid = threadIdx.x;
    const int tf  = n & 7;

    // ---- stage 16px x 256c tile (bf16, transposed, swizzled) --------------
    f32x4 va[2], vb[2];
    int   cps[2], pss[2];
    #pragma unroll
    for (int i = 0; i < 2; ++i) {
        const int idx = tid + i * 256;      // 0..511 = (cp 0..127) x (ps 0..3)
        const int cp  = idx >> 2;
        const int ps  = idx & 3;
        cps[i] = cp; pss[i] = ps;
        const int c0 = cp * 2;              // pair (c0, c0+1), same fold region
        int  d; bool valid;
        if (c0 < 32)      { d = -1; valid = (tf > 0); }
        else if (c0 < 64) { d =  1; valid = (tf < 7); }
        else              { d =  0; valid = true;     }
        const float* src = x + ((size_t)(n + (valid ? d : 0)) * CDIM + c0) * HWPX
                             + p0 + ps * 4;
        f32x4 a = {0.f, 0.f, 0.f, 0.f};
        f32x4 b = {0.f, 0.f, 0.f, 0.f};
        if (valid) {
            a = *(const f32x4*)src;
            b = *(const f32x4*)(src + HWPX);
        }
        va[i] = a; vb[i] = b;
    }
    #pragma unroll
    for (int i = 0; i < 2; ++i) {
        const int c0 = cps[i] * 2;
        const int ps = pss[i];
        #pragma unroll
        for (int r = 0; r < 4; ++r) {
            const int p  = ps * 4 + r;          // p & 3 == r
            const int cc = c0 ^ (r << 5);       // swizzle on bf16 bits 5..6
            *(unsigned int*)&y[p * LROW + cc] = pk2(va[i][r], vb[i][r]);
        }
    }
    __syncthreads();

    // ---- MFMA: D[o, p] = W[o,:] x Y[:,p]; wave wv owns 64 out-channels ----
    const int lane = tid & 63;
    const int wv   = tid >> 6;
    const int g    = lane >> 4;
    const int ol   = lane & 15;

    f32x4 acc[4];
    #pragma unroll
    for (int m = 0; m < 4; ++m) acc[m] = f32x4{0.f, 0.f, 0.f, 0.f};

    #pragma unroll
    for (int kk = 0; kk < 8; ++kk) {
        const int c  = kk * 32 + g * 8;         // k = g*8 + j, A and B alike
        const int cc = c ^ ((ol & 3) << 5);     // matches write swizzle (p=ol)
        const bf16x8 bfrag = *(const bf16x8*)&y[ol * LROW + cc];
        #pragma unroll
        for (int m = 0; m < 4; ++m) {
            const int o = wv * 64 + m * 16 + ol;    // A row on lane&15
            const bf16x8 af = *(const bf16x8*)&wb[(size_t)o * CDIM + c];
            acc[m] = __builtin_amdgcn_mfma_f32_16x16x32_bf16(af, bfrag, acc[m], 0, 0, 0);
        }
    }

    // ---- epilogue: C/D col=lane&15 (pixel), row=(lane>>4)*4+r (channel) ---
    float* ob = out + (size_t)n * FRST + p0 + ol;
    #pragma unroll
    for (int m = 0; m < 4; ++m) {
        #pragma unroll
        for (int r = 0; r < 4; ++r) {
            const int o = wv * 64 + m * 16 + g * 4 + r;
            ob[(size_t)o * HWPX] = acc[m][r];
        }
    }
}

// ---- fallback (no workspace): R3 kernel, known-correct ---------------------
#define P_TILE 112
#define LDS_STRIDE 264
__global__ __launch_bounds__(512, 4)
void tsm_fallback(const float* __restrict__ x, const float* __restrict__ w,
                  float* __restrict__ out) {
    __shared__ __align__(16) unsigned short ylds[P_TILE * LDS_STRIDE];
    const int n = blockIdx.x, tile = blockIdx.y, p0 = tile * P_TILE;
    const int tid = threadIdx.x, tf = n & 7;
    f32x4 v0[7], v1[7]; int cps[7], pvs[7];
    #pragma unroll
    for (int i = 0; i < 7; ++i) {
        const int idx = tid + i * 512, cp = idx / 28, pv = idx - cp * 28;
        cps[i] = cp; pvs[i] = pv;
        const int c0 = cp * 2;
        int nsrc; bool valid;
        if (c0 < 32)      { nsrc = n - 1; valid = (tf > 0); }
        else if (c0 < 64) { nsrc = n + 1; valid = (tf < 7); }
        else              { nsrc = n;     valid = true; }
        const float* src = x + ((size_t)(valid ? nsrc : n) * CDIM + c0) * HWPX + p0 + pv * 4;
        f32x4 a = {0,0,0,0}, b = {0,0,0,0};
        if (valid) { a = *(const f32x4*)src; b = *(const f32x4*)(src + HWPX); }
        v0[i] = a; v1[i] = b;
    }
    #pragma unroll
    for (int i = 0; i < 7; ++i) {
        const int c0 = cps[i] * 2, pv = pvs[i];
        const int cc = c0 ^ ((pv & 7) << 3);
        const int rb = pv * 4 * LDS_STRIDE + cc;
        #pragma unroll
        for (int r = 0; r < 4; ++r)
            *(unsigned int*)&ylds[rb + r * LDS_STRIDE] = pk2(v0[i][r], v1[i][r]);
    }
    __syncthreads();
    const int lane = tid & 63, wv = tid >> 6, g = lane >> 4, ol = lane & 15;
    f32x4 acc[2][7];
    #pragma unroll
    for (int m = 0; m < 2; ++m)
        #pragma unroll
        for (int nn = 0; nn < 7; ++nn) acc[m][nn] = f32x4{0,0,0,0};
    #pragma unroll
    for (int kk = 0; kk < 8; ++kk) {
        const int c = kk * 32 + g * 8;
        bf16x8 af[2];
        #pragma unroll
        for (int m = 0; m < 2; ++m) {
            const float* wp = w + (size_t)(wv * 32 + m * 16 + ol) * CDIM + c;
            f32x4 w0 = *(const f32x4*)wp, w1 = *(const f32x4*)(wp + 4);
            union { bf16x8 v; unsigned int u4[4]; } cv;
            cv.u4[0] = pk2(w0[0], w0[1]); cv.u4[1] = pk2(w0[2], w0[3]);
            cv.u4[2] = pk2(w1[0], w1[1]); cv.u4[3] = pk2(w1[2], w1[3]);
            af[m] = cv.v;
        }
        #pragma unroll
        for (int nn = 0; nn < 7; ++nn) {
            const int p = nn * 16 + ol;
            const int cc = c ^ (((p >> 2) & 7) << 3);
            const bf16x8 bf = *(const bf16x8*)&ylds[p * LDS_STRIDE + cc];
            #pragma unroll
            for (int m = 0; m < 2; ++m)
                acc[m][nn] = __builtin_amdgcn_mfma_f32_16x16x32_bf16(af[m], bf, acc[m][nn], 0, 0, 0);
        }
    }
    const size_t outbase = (size_t)n * CDIM * HWPX + p0 + ol;
    #pragma unroll
    for (int m = 0; m < 2; ++m)
        #pragma unroll
        for (int r = 0; r < 4; ++r) {
            const int o = wv * 32 + m * 16 + g * 4 + r;
            float* orow = out + outbase + (size_t)o * HWPX;
            #pragma unroll
            for (int nn = 0; nn < 7; ++nn) orow[nn * 16] = acc[m][nn][r];
        }
}

extern "C" void kernel_launch(void* const* d_in, const int* in_sizes, int n_in,
                              void* d_out, int out_size, void* d_ws, size_t ws_size,
                              hipStream_t stream) {
    const float* x = (const float*)d_in[0];
    const float* w = (const float*)d_in[1];
    float* out     = (float*)d_out;
    const size_t wb_bytes = (size_t)CDIM * CDIM * sizeof(unsigned short); // 128KB
    if (ws_size >= wb_bytes) {
        unsigned short* wbuf = (unsigned short*)d_ws;
        wconv<<<64, 256, 0, stream>>>(w, wbuf);
        tsm_tlp<<<NWG, 256, 0, stream>>>(x, wbuf, out);
    } else {
        tsm_fallback<<<dim3(128, 7, 1), dim3(512, 1, 1), 0, stream>>>(x, w, out);
    }
}

// Round 6
// 60.364 us; speedup vs baseline: 1.8255x; 1.8255x over previous
//
#include <hip/hip_runtime.h>
#include <hip/hip_bf16.h>

// TSM temporal shift + 1x1 conv (256->256) fused as bf16 MFMA GEMM.
// x: [128, 256, 28, 28] f32, w: [256, 256] f32, out: [128, 256, 28, 28] f32.
// out[n,o,p] = sum_c W[o,c] * Y_n[c,p],
//   Y_n[c,p] = x[n-1,c,p] (c<32, t>0), x[n+1,c,p] (32<=c<64, t<7), x[n,c,p] else.
//
// R6: W-in-VGPR persistent pipeline.
//  - 1024 persistent blocks (4/CU), 256 thr / 4 waves; block = (o-half, tile
//    stream). Each wave holds its 32-row W panel in 64 VGPRs, loaded ONCE ->
//    compute phase has zero global loads (R5 failure: per-tile W reload from
//    L2, serialized at VGPR=32).
//  - Tile = 16 px x 256 c; 49 tiles/frame divides evenly -> all tile indexing
//    is wave-uniform (SGPR), advanced incrementally.
//  - 1-deep prefetch via asm global_load_dwordx4 (R4-proven), vmcnt(8) leaves
//    the 8 output stores in flight while draining the 4 loads.
//  - LDS double buffer 2x16x264 bf16 (16.9 KB); R5's verified swizzle
//    cc = c ^ ((p&3)<<5): b128 reads uniform 8/bank (optimal), b32 writes 2-way.

#define CDIM 256
#define HWPX 784
#define FRST (CDIM * HWPX)        // 200704 floats per frame
#define NPT  49                   // 16-px tiles per frame
#define NT   (128 * NPT)          // 6272 tiles
#define NHB  512                  // blocks per o-half
#define LROW 264                  // bf16 per LDS pixel row (528 B)

using bf16x8 = __attribute__((ext_vector_type(8))) short;
using f32x4  = __attribute__((ext_vector_type(4))) float;

static __device__ __forceinline__ unsigned int pk2(float lo, float hi) {
    union { __hip_bfloat162 h; unsigned int u; } cv;
    cv.h = __float22bfloat162_rn(make_float2(lo, hi));
    return cv.u;
}

// ---- W f32 -> bf16 row-major (one-shot) ------------------------------------
__global__ void wconv(const float* __restrict__ w, unsigned short* __restrict__ wb) {
    const int i = (blockIdx.x * 256 + threadIdx.x) * 4;
    f32x4 v = *(const f32x4*)(w + i);
    *(uint2*)(wb + i) = make_uint2(pk2(v[0], v[1]), pk2(v[2], v[3]));
}

__global__ __launch_bounds__(256, 4)   // <=128 VGPR -> 4 waves/SIMD, 4 blocks/CU
void tsm_wreg(const float* __restrict__ x,
              const unsigned short* __restrict__ wb,
              float* __restrict__ out) {
    __shared__ __align__(16) unsigned short y[2][16 * LROW];   // 16896 B

    // block decode: co-locate the two o-halves of a tile stream on one XCD
    const int b    = blockIdx.x;
    const int rest = b >> 3;
    const int h    = rest & 1;                  // o-half: 0 -> o<128, 1 -> o>=128
    const int tb   = (b & 7) + 8 * (rest >> 1); // tile stream 0..511

    const int tid  = threadIdx.x;
    const int lane = tid & 63;
    const int wv   = tid >> 6;
    const int g    = lane >> 4;
    const int ol   = lane & 15;

    // ---- W panel into VGPRs (once): wave owns o = h*128 + wv*32 + [0,32) --
    bf16x8 wf[8][2];
    #pragma unroll
    for (int kk = 0; kk < 8; ++kk)
        #pragma unroll
        for (int m = 0; m < 2; ++m)
            wf[kk][m] = *(const bf16x8*)
                &wb[(size_t)(h * 128 + wv * 32 + m * 16 + ol) * CDIM + kk * 32 + g * 8];

    // ---- staging thread constants ----------------------------------------
    const int ps  = tid & 3;          // vec4 slot (4 px)
    const int cp0 = tid >> 2;         // 0..63; channels 2cp0, 2cp0+1, +128, +129
    const int c00 = cp0 * 2;
    const int d0  = (cp0 < 16) ? -1 : (cp0 < 32 ? 1 : 0);   // fold shift, i=0 pair
    const int off00 = c00 * HWPX + ps * 4 + d0 * FRST;      // may be negative
    const int off10 = (c00 + 128) * HWPX + ps * 4;
    // LDS write base (bf16 units), swizzle applied per element e
    const int wbase = ps * 4 * LROW;

    // out addressing: per-thread constant part
    const int oc = ol + (h * 128 + wv * 32 + g * 4) * HWPX;

    // ---- uniform tile state ----------------------------------------------
    int t  = tb;
    int n  = t / NPT;
    int pt = t - n * NPT;
    long u = (long)n * FRST + pt * 16;   // frame/pixel base (floats)
    int tf = n & 7;

    f32x4 rv0, rv1, rv2, rv3;

    #define STAGE_ISSUE(U, TF)                                                 \
    {                                                                          \
        const bool v0 = !((d0 == -1 && (TF) == 0) || (d0 == 1 && (TF) == 7));  \
        const float* bp = x + (U);                                             \
        if (v0) {                                                              \
            const float* p0_ = bp + off00;                                     \
            const float* p1_ = p0_ + HWPX;                                     \
            asm volatile("global_load_dwordx4 %0, %1, off" : "=v"(rv0) : "v"(p0_)); \
            asm volatile("global_load_dwordx4 %0, %1, off" : "=v"(rv1) : "v"(p1_)); \
        } else {                                                               \
            rv0 = f32x4{0.f, 0.f, 0.f, 0.f};                                   \
            rv1 = f32x4{0.f, 0.f, 0.f, 0.f};                                   \
        }                                                                      \
        const float* p2_ = bp + off10;                                         \
        const float* p3_ = p2_ + HWPX;                                         \
        asm volatile("global_load_dwordx4 %0, %1, off" : "=v"(rv2) : "v"(p2_)); \
        asm volatile("global_load_dwordx4 %0, %1, off" : "=v"(rv3) : "v"(p3_)); \
    }

    #define WRITE_LDS(CUR)                                                     \
    {                                                                          \
        unsigned short* yb = &y[(CUR)][0];                                     \
        _Pragma("unroll")                                                      \
        for (int e = 0; e < 4; ++e) {                                          \
            const int cc = c00 ^ (e << 5);                                     \
            *(unsigned int*)&yb[wbase + e * LROW + cc]       = pk2(rv0[e], rv1[e]); \
            *(unsigned int*)&yb[wbase + e * LROW + cc + 128] = pk2(rv2[e], rv3[e]); \
        }                                                                      \
    }

    // ---- prologue ---------------------------------------------------------
    STAGE_ISSUE(u, tf);
    asm volatile("s_waitcnt vmcnt(0)" ::: "memory");
    __builtin_amdgcn_sched_barrier(0);
    WRITE_LDS(0);
    __syncthreads();

    int cur = 0;
    while (1) {
        const int  tn   = t + NHB;
        const bool more = (tn < NT);
        long un = u; int nf2 = n, pt2 = pt, tfn = tf;
        if (more) {
            nf2 = n + 10; pt2 = pt + 22;          // 512 = 10*49 + 22
            if (pt2 >= NPT) { pt2 -= NPT; nf2 += 1; }
            un  = (long)nf2 * FRST + pt2 * 16;
            tfn = nf2 & 7;
            STAGE_ISSUE(un, tfn);
        }

        // ---- compute tile t from y[cur] (no global loads) -----------------
        f32x4 acc0 = {0.f, 0.f, 0.f, 0.f};
        f32x4 acc1 = {0.f, 0.f, 0.f, 0.f};
        const unsigned short* yr = &y[cur][0];
        #pragma unroll
        for (int kk = 0; kk < 8; ++kk) {
            const int c  = kk * 32 + g * 8;
            const int cc = c ^ ((ol & 3) << 5);
            const bf16x8 bf = *(const bf16x8*)&yr[ol * LROW + cc];
            acc0 = __builtin_amdgcn_mfma_f32_16x16x32_bf16(wf[kk][0], bf, acc0, 0, 0, 0);
            acc1 = __builtin_amdgcn_mfma_f32_16x16x32_bf16(wf[kk][1], bf, acc1, 0, 0, 0);
        }

        // ---- store (8 dwords; left in flight past the vmcnt below) --------
        {
            float* ob = out + u + oc;
            #pragma unroll
            for (int r = 0; r < 4; ++r) {
                ob[(size_t)(r)      * HWPX] = acc0[r];
                ob[(size_t)(r + 16) * HWPX] = acc1[r];
            }
        }

        if (!more) break;
        asm volatile("s_waitcnt vmcnt(8)" ::: "memory");   // drain 4 loads only
        __builtin_amdgcn_sched_barrier(0);
        WRITE_LDS(cur ^ 1);
        __syncthreads();
        cur ^= 1; t = tn; u = un; n = nf2; pt = pt2; tf = tfn;
    }
    #undef STAGE_ISSUE
    #undef WRITE_LDS
}

// ---- fallback (no workspace): R3 kernel, known-correct ---------------------
#define P_TILE 112
#define LDS_STRIDE 264
__global__ __launch_bounds__(512, 4)
void tsm_fallback(const float* __restrict__ x, const float* __restrict__ w,
                  float* __restrict__ out) {
    __shared__ __align__(16) unsigned short ylds[P_TILE * LDS_STRIDE];
    const int n = blockIdx.x, tile = blockIdx.y, p0 = tile * P_TILE;
    const int tid = threadIdx.x, tf = n & 7;
    f32x4 v0[7], v1[7]; int cps[7], pvs[7];
    #pragma unroll
    for (int i = 0; i < 7; ++i) {
        const int idx = tid + i * 512, cp = idx / 28, pv = idx - cp * 28;
        cps[i] = cp; pvs[i] = pv;
        const int c0 = cp * 2;
        int nsrc; bool valid;
        if (c0 < 32)      { nsrc = n - 1; valid = (tf > 0); }
        else if (c0 < 64) { nsrc = n + 1; valid = (tf < 7); }
        else              { nsrc = n;     valid = true; }
        const float* src = x + ((size_t)(valid ? nsrc : n) * CDIM + c0) * HWPX + p0 + pv * 4;
        f32x4 a = {0,0,0,0}, b = {0,0,0,0};
        if (valid) { a = *(const f32x4*)src; b = *(const f32x4*)(src + HWPX); }
        v0[i] = a; v1[i] = b;
    }
    #pragma unroll
    for (int i = 0; i < 7; ++i) {
        const int c0 = cps[i] * 2, pv = pvs[i];
        const int cc = c0 ^ ((pv & 7) << 3);
        const int rb = pv * 4 * LDS_STRIDE + cc;
        #pragma unroll
        for (int r = 0; r < 4; ++r)
            *(unsigned int*)&ylds[rb + r * LDS_STRIDE] = pk2(v0[i][r], v1[i][r]);
    }
    __syncthreads();
    const int lane = tid & 63, wv = tid >> 6, g = lane >> 4, ol = lane & 15;
    f32x4 acc[2][7];
    #pragma unroll
    for (int m = 0; m < 2; ++m)
        #pragma unroll
        for (int nn = 0; nn < 7; ++nn) acc[m][nn] = f32x4{0,0,0,0};
    #pragma unroll
    for (int kk = 0; kk < 8; ++kk) {
        const int c = kk * 32 + g * 8;
        bf16x8 af[2];
        #pragma unroll
        for (int m = 0; m < 2; ++m) {
            const float* wp = w + (size_t)(wv * 32 + m * 16 + ol) * CDIM + c;
            f32x4 w0 = *(const f32x4*)wp, w1 = *(const f32x4*)(wp + 4);
            union { bf16x8 v; unsigned int u4[4]; } cv;
            cv.u4[0] = pk2(w0[0], w0[1]); cv.u4[1] = pk2(w0[2], w0[3]);
            cv.u4[2] = pk2(w1[0], w1[1]); cv.u4[3] = pk2(w1[2], w1[3]);
            af[m] = cv.v;
        }
        #pragma unroll
        for (int nn = 0; nn < 7; ++nn) {
            const int p = nn * 16 + ol;
            const int cc = c ^ (((p >> 2) & 7) << 3);
            const bf16x8 bf = *(const bf16x8*)&ylds[p * LDS_STRIDE + cc];
            #pragma unroll
            for (int m = 0; m < 2; ++m)
                acc[m][nn] = __builtin_amdgcn_mfma_f32_16x16x32_bf16(af[m], bf, acc[m][nn], 0, 0, 0);
        }
    }
    const size_t outbase = (size_t)n * CDIM * HWPX + p0 + ol;
    #pragma unroll
    for (int m = 0; m < 2; ++m)
        #pragma unroll
        for (int r = 0; r < 4; ++r) {
            const int o = wv * 32 + m * 16 + g * 4 + r;
            float* orow = out + outbase + (size_t)o * HWPX;
            #pragma unroll
            for (int nn = 0; nn < 7; ++nn) orow[nn * 16] = acc[m][nn][r];
        }
}

extern "C" void kernel_launch(void* const* d_in, const int* in_sizes, int n_in,
                              void* d_out, int out_size, void* d_ws, size_t ws_size,
                              hipStream_t stream) {
    const float* x = (const float*)d_in[0];
    const float* w = (const float*)d_in[1];
    float* out     = (float*)d_out;
    const size_t wb_bytes = (size_t)CDIM * CDIM * sizeof(unsigned short); // 128KB
    if (ws_size >= wb_bytes) {
        unsigned short* wbuf = (unsigned short*)d_ws;
        wconv<<<64, 256, 0, stream>>>(w, wbuf);
        tsm_wreg<<<1024, 256, 0, stream>>>(x, wbuf, out);
    } else {
        tsm_fallback<<<dim3(128, 7, 1), dim3(512, 1, 1), 0, stream>>>(x, w, out);
    }
}

// Round 7
// 59.967 us; speedup vs baseline: 1.8376x; 1.0066x over previous
//
#include <hip/hip_runtime.h>
#include <hip/hip_bf16.h>

// TSM temporal shift + 1x1 conv (256->256) fused as bf16 MFMA GEMM.
// x: [128, 256, 28, 28] f32, w: [256, 256] f32, out: [128, 256, 28, 28] f32.
// out[n,o,p] = sum_c W[o,c] * Y_n[c,p],
//   Y_n[c,p] = x[n-1,c,p] (c<32, t>0), x[n+1,c,p] (32<=c<64, t<7), x[n,c,p] else.
//
// R7 = R6 + asm-pinned W panel.
//  R6 showed VGPR=64: the compiler sank the wf loads back into the loop, so
//  every tile re-read 16KB of W from L2 on the MFMA critical path. Asm-issued
//  global_load_dwordx4 results cannot be rematerialized -> W stays in VGPRs
//  for the whole persistent block. Everything else is the verified R6
//  pipeline: 1024 persistent blocks (4/CU), 16px x 256c tiles, 1-deep asm
//  prefetch, vmcnt(8) leaves stores in flight, swizzle cc = c ^ ((p&3)<<5).

#define CDIM 256
#define HWPX 784
#define FRST (CDIM * HWPX)        // 200704 floats per frame
#define NPT  49                   // 16-px tiles per frame
#define NT   (128 * NPT)          // 6272 tiles
#define NHB  512                  // blocks per o-half
#define LROW 264                  // bf16 per LDS pixel row (528 B)

using bf16x8 = __attribute__((ext_vector_type(8))) short;
using f32x4  = __attribute__((ext_vector_type(4))) float;

static __device__ __forceinline__ unsigned int pk2(float lo, float hi) {
    union { __hip_bfloat162 h; unsigned int u; } cv;
    cv.h = __float22bfloat162_rn(make_float2(lo, hi));
    return cv.u;
}

// ---- W f32 -> bf16 row-major (one-shot) ------------------------------------
__global__ void wconv(const float* __restrict__ w, unsigned short* __restrict__ wb) {
    const int i = (blockIdx.x * 256 + threadIdx.x) * 4;
    f32x4 v = *(const f32x4*)(w + i);
    *(uint2*)(wb + i) = make_uint2(pk2(v[0], v[1]), pk2(v[2], v[3]));
}

__global__ __launch_bounds__(256, 4)   // <=128 VGPR -> 4 waves/SIMD, 4 blocks/CU
void tsm_wreg(const float* __restrict__ x,
              const unsigned short* __restrict__ wb,
              float* __restrict__ out) {
    __shared__ __align__(16) unsigned short y[2][16 * LROW];   // 16896 B

    // block decode: co-locate the two o-halves of a tile stream on one XCD
    const int b    = blockIdx.x;
    const int rest = b >> 3;
    const int h    = rest & 1;                  // o-half: 0 -> o<128, 1 -> o>=128
    const int tb   = (b & 7) + 8 * (rest >> 1); // tile stream 0..511

    const int tid  = threadIdx.x;
    const int lane = tid & 63;
    const int wv   = tid >> 6;
    const int g    = lane >> 4;
    const int ol   = lane & 15;

    // ---- W panel into VGPRs (once, asm-pinned so it cannot be sunk) -------
    bf16x8 wf[8][2];
    #pragma unroll
    for (int kk = 0; kk < 8; ++kk)
        #pragma unroll
        for (int m = 0; m < 2; ++m) {
            const unsigned short* wp =
                &wb[(size_t)(h * 128 + wv * 32 + m * 16 + ol) * CDIM + kk * 32 + g * 8];
            asm volatile("global_load_dwordx4 %0, %1, off"
                         : "=v"(wf[kk][m]) : "v"(wp));
        }

    // ---- staging thread constants ----------------------------------------
    const int ps  = tid & 3;          // vec4 slot (4 px)
    const int cp0 = tid >> 2;         // 0..63; channels 2cp0, 2cp0+1, +128, +129
    const int c00 = cp0 * 2;
    const int d0  = (cp0 < 16) ? -1 : (cp0 < 32 ? 1 : 0);   // fold shift, i=0 pair
    const int off00 = c00 * HWPX + ps * 4 + d0 * FRST;      // may be negative
    const int off10 = (c00 + 128) * HWPX + ps * 4;
    const int wbase = ps * 4 * LROW;  // LDS write base (bf16 units)

    // out addressing: per-thread constant part
    const int oc = ol + (h * 128 + wv * 32 + g * 4) * HWPX;

    // ---- uniform tile state ----------------------------------------------
    int t  = tb;
    int n  = t / NPT;
    int pt = t - n * NPT;
    long u = (long)n * FRST + pt * 16;   // frame/pixel base (floats)
    int tf = n & 7;

    f32x4 rv0, rv1, rv2, rv3;

    #define STAGE_ISSUE(U, TF)                                                 \
    {                                                                          \
        const bool v0 = !((d0 == -1 && (TF) == 0) || (d0 == 1 && (TF) == 7));  \
        const float* bp = x + (U);                                             \
        if (v0) {                                                              \
            const float* p0_ = bp + off00;                                     \
            const float* p1_ = p0_ + HWPX;                                     \
            asm volatile("global_load_dwordx4 %0, %1, off" : "=v"(rv0) : "v"(p0_)); \
            asm volatile("global_load_dwordx4 %0, %1, off" : "=v"(rv1) : "v"(p1_)); \
        } else {                                                               \
            rv0 = f32x4{0.f, 0.f, 0.f, 0.f};                                   \
            rv1 = f32x4{0.f, 0.f, 0.f, 0.f};                                   \
        }                                                                      \
        const float* p2_ = bp + off10;                                         \
        const float* p3_ = p2_ + HWPX;                                         \
        asm volatile("global_load_dwordx4 %0, %1, off" : "=v"(rv2) : "v"(p2_)); \
        asm volatile("global_load_dwordx4 %0, %1, off" : "=v"(rv3) : "v"(p3_)); \
    }

    #define WRITE_LDS(CUR)                                                     \
    {                                                                          \
        unsigned short* yb = &y[(CUR)][0];                                     \
        _Pragma("unroll")                                                      \
        for (int e = 0; e < 4; ++e) {                                          \
            const int cc = c00 ^ (e << 5);                                     \
            *(unsigned int*)&yb[wbase + e * LROW + cc]       = pk2(rv0[e], rv1[e]); \
            *(unsigned int*)&yb[wbase + e * LROW + cc + 128] = pk2(rv2[e], rv3[e]); \
        }                                                                      \
    }

    // ---- prologue: stage tile t into buf 0 (drains wf loads too) ----------
    STAGE_ISSUE(u, tf);
    asm volatile("s_waitcnt vmcnt(0)" ::: "memory");
    __builtin_amdgcn_sched_barrier(0);
    WRITE_LDS(0);
    __syncthreads();

    int cur = 0;
    while (1) {
        const int  tn   = t + NHB;
        const bool more = (tn < NT);
        long un = u; int nf2 = n, pt2 = pt, tfn = tf;
        if (more) {
            nf2 = n + 10; pt2 = pt + 22;          // 512 = 10*49 + 22
            if (pt2 >= NPT) { pt2 -= NPT; nf2 += 1; }
            un  = (long)nf2 * FRST + pt2 * 16;
            tfn = nf2 & 7;
            STAGE_ISSUE(un, tfn);
        }

        // ---- compute tile t from y[cur] (zero global loads) ---------------
        f32x4 acc0 = {0.f, 0.f, 0.f, 0.f};
        f32x4 acc1 = {0.f, 0.f, 0.f, 0.f};
        const unsigned short* yr = &y[cur][0];
        #pragma unroll
        for (int kk = 0; kk < 8; ++kk) {
            const int c  = kk * 32 + g * 8;
            const int cc = c ^ ((ol & 3) << 5);
            const bf16x8 bf = *(const bf16x8*)&yr[ol * LROW + cc];
            acc0 = __builtin_amdgcn_mfma_f32_16x16x32_bf16(wf[kk][0], bf, acc0, 0, 0, 0);
            acc1 = __builtin_amdgcn_mfma_f32_16x16x32_bf16(wf[kk][1], bf, acc1, 0, 0, 0);
        }

        // ---- store (8 dwords; left in flight past the vmcnt below) --------
        {
            float* ob = out + u + oc;
            #pragma unroll
            for (int r = 0; r < 4; ++r) {
                ob[(size_t)(r)      * HWPX] = acc0[r];
                ob[(size_t)(r + 16) * HWPX] = acc1[r];
            }
        }

        if (!more) break;
        asm volatile("s_waitcnt vmcnt(8)" ::: "memory");   // drain 4 loads only
        __builtin_amdgcn_sched_barrier(0);
        WRITE_LDS(cur ^ 1);
        __syncthreads();
        cur ^= 1; t = tn; u = un; n = nf2; pt = pt2; tf = tfn;
    }
    #undef STAGE_ISSUE
    #undef WRITE_LDS
}

// ---- fallback (no workspace): R3 kernel, known-correct ---------------------
#define P_TILE 112
#define LDS_STRIDE 264
__global__ __launch_bounds__(512, 4)
void tsm_fallback(const float* __restrict__ x, const float* __restrict__ w,
                  float* __restrict__ out) {
    __shared__ __align__(16) unsigned short ylds[P_TILE * LDS_STRIDE];
    const int n = blockIdx.x, tile = blockIdx.y, p0 = tile * P_TILE;
    const int tid = threadIdx.x, tf = n & 7;
    f32x4 v0[7], v1[7]; int cps[7], pvs[7];
    #pragma unroll
    for (int i = 0; i < 7; ++i) {
        const int idx = tid + i * 512, cp = idx / 28, pv = idx - cp * 28;
        cps[i] = cp; pvs[i] = pv;
        const int c0 = cp * 2;
        int nsrc; bool valid;
        if (c0 < 32)      { nsrc = n - 1; valid = (tf > 0); }
        else if (c0 < 64) { nsrc = n + 1; valid = (tf < 7); }
        else              { nsrc = n;     valid = true; }
        const float* src = x + ((size_t)(valid ? nsrc : n) * CDIM + c0) * HWPX + p0 + pv * 4;
        f32x4 a = {0,0,0,0}, b = {0,0,0,0};
        if (valid) { a = *(const f32x4*)src; b = *(const f32x4*)(src + HWPX); }
        v0[i] = a; v1[i] = b;
    }
    #pragma unroll
    for (int i = 0; i < 7; ++i) {
        const int c0 = cps[i] * 2, pv = pvs[i];
        const int cc = c0 ^ ((pv & 7) << 3);
        const int rb = pv * 4 * LDS_STRIDE + cc;
        #pragma unroll
        for (int r = 0; r < 4; ++r)
            *(unsigned int*)&ylds[rb + r * LDS_STRIDE] = pk2(v0[i][r], v1[i][r]);
    }
    __syncthreads();
    const int lane = tid & 63, wv = tid >> 6, g = lane >> 4, ol = lane & 15;
    f32x4 acc[2][7];
    #pragma unroll
    for (int m = 0; m < 2; ++m)
        #pragma unroll
        for (int nn = 0; nn < 7; ++nn) acc[m][nn] = f32x4{0,0,0,0};
    #pragma unroll
    for (int kk = 0; kk < 8; ++kk) {
        const int c = kk * 32 + g * 8;
        bf16x8 af[2];
        #pragma unroll
        for (int m = 0; m < 2; ++m) {
            const float* wp = w + (size_t)(wv * 32 + m * 16 + ol) * CDIM + c;
            f32x4 w0 = *(const f32x4*)wp, w1 = *(const f32x4*)(wp + 4);
            union { bf16x8 v; unsigned int u4[4]; } cv;
            cv.u4[0] = pk2(w0[0], w0[1]); cv.u4[1] = pk2(w0[2], w0[3]);
            cv.u4[2] = pk2(w1[0], w1[1]); cv.u4[3] = pk2(w1[2], w1[3]);
            af[m] = cv.v;
        }
        #pragma unroll
        for (int nn = 0; nn < 7; ++nn) {
            const int p = nn * 16 + ol;
            const int cc = c ^ (((p >> 2) & 7) << 3);
            const bf16x8 bf = *(const bf16x8*)&ylds[p * LDS_STRIDE + cc];
            #pragma unroll
            for (int m = 0; m < 2; ++m)
                acc[m][nn] = __builtin_amdgcn_mfma_f32_16x16x32_bf16(af[m], bf, acc[m][nn], 0, 0, 0);
        }
    }
    const size_t outbase = (size_t)n * CDIM * HWPX + p0 + ol;
    #pragma unroll
    for (int m = 0; m < 2; ++m)
        #pragma unroll
        for (int r = 0; r < 4; ++r) {
            const int o = wv * 32 + m * 16 + g * 4 + r;
            float* orow = out + outbase + (size_t)o * HWPX;
            #pragma unroll
            for (int nn = 0; nn < 7; ++nn) orow[nn * 16] = acc[m][nn][r];
        }
}

extern "C" void kernel_launch(void* const* d_in, const int* in_sizes, int n_in,
                              void* d_out, int out_size, void* d_ws, size_t ws_size,
                              hipStream_t stream) {
    const float* x = (const float*)d_in[0];
    const float* w = (const float*)d_in[1];
    float* out     = (float*)d_out;
    const size_t wb_bytes = (size_t)CDIM * CDIM * sizeof(unsigned short); // 128KB
    if (ws_size >= wb_bytes) {
        unsigned short* wbuf = (unsigned short*)d_ws;
        wconv<<<64, 256, 0, stream>>>(w, wbuf);
        tsm_wreg<<<1024, 256, 0, stream>>>(x, wbuf, out);
    } else {
        tsm_fallback<<<dim3(128, 7, 1), dim3(512, 1, 1), 0, stream>>>(x, w, out);
    }
}

// Round 9
// 50.436 us; speedup vs baseline: 2.1849x; 1.1890x over previous
//
#include <hip/hip_runtime.h>
#include <hip/hip_bf16.h>

// TSM temporal shift + 1x1 conv (256->256) fused as bf16 MFMA GEMM.
// x: [128, 256, 28, 28] f32, w: [256, 256] f32, out: [128, 256, 28, 28] f32.
// out[n,o,p] = sum_c W[o,c] * Y_n[c,p],
//   Y_n[c,p] = x[n-1,c,p] (c<32, t>0), x[n+1,c,p] (32<=c<64, t<7), x[n,c,p] else.
//
// R9: deep single-shot staging (no multi-tile pipeline).
//  - Block = (frame n, 112-px tile, o-half). 1792 blocks, 256 thr / 4 waves.
//  - 28 asm global_load_dwordx4 per thread issued back-to-back: 28KB in
//    flight per wave (R7 had 4KB -> 54% of achievable BW; this is the lever).
//  - __launch_bounds__(256,2): 256-reg cap. Peak live = staged 112 + wf 64 +
//    ~25 misc = ~201 < 256 (R8 crashed at forced-live > the 128 cap).
//  - W panel asm-pinned once (64 regs); compute phase has zero global loads.
//  - R2/R3-verified LDS swizzle: write cc = c0 ^ ((pv&7)<<3), read
//    cc = c ^ (((p>>2)&7)<<3); b128 reads 16B-aligned.
//  - o-half twin blocks adjacent on the same XCD (bijective chunked swizzle,
//    1792 % 8 == 0) -> duplicate x-tile read is an L2 hit; HBM stays ~202MB.

#define CDIM 256
#define HWPX 784
#define FRST (CDIM * HWPX)        // 200704 floats per frame
#define P_TILE 112
#define NPT  7                    // 112-px tiles per frame
#define NWG  (128 * NPT * 2)      // 1792 blocks (x2 o-halves), % 8 == 0
#define LROW 264                  // bf16 per LDS pixel row (528 B = 33*16B)

using bf16x8 = __attribute__((ext_vector_type(8))) short;
using f32x4  = __attribute__((ext_vector_type(4))) float;

static __device__ __forceinline__ unsigned int pk2(float lo, float hi) {
    union { __hip_bfloat162 h; unsigned int u; } cv;
    cv.h = __float22bfloat162_rn(make_float2(lo, hi));
    return cv.u;
}

// ---- W f32 -> bf16 row-major (one-shot) ------------------------------------
__global__ void wconv(const float* __restrict__ w, unsigned short* __restrict__ wb) {
    const int i = (blockIdx.x * 256 + threadIdx.x) * 4;
    f32x4 v = *(const f32x4*)(w + i);
    *(uint2*)(wb + i) = make_uint2(pk2(v[0], v[1]), pk2(v[2], v[3]));
}

__global__ __launch_bounds__(256, 2)   // 256-reg budget: deep staging, no spill
void tsm_deep(const float* __restrict__ x,
              const unsigned short* __restrict__ wb,
              float* __restrict__ out) {
    __shared__ __align__(16) unsigned short y[P_TILE * LROW];   // 59136 B

    // bijective XCD-chunked decode; twin o-halves adjacent (same XCD, ~same time)
    const int bid = blockIdx.x;
    const int wg  = (bid & 7) * (NWG / 8) + (bid >> 3);
    const int h    = wg & 1;              // o-half
    const int pair = wg >> 1;             // 0..895
    const int n    = pair / NPT;          // frame
    const int pt   = pair - n * NPT;      // 0..6
    const int p0   = pt * P_TILE;
    const int tid  = threadIdx.x;
    const int tf   = n & 7;

    const int lane = tid & 63;
    const int wv   = tid >> 6;            // wave -> 32 o-channels within half
    const int g    = lane >> 4;
    const int ol   = lane & 15;

    // ---- W panel (asm-pinned once; 64 regs) -------------------------------
    bf16x8 wf[8][2];
    #pragma unroll
    for (int kk = 0; kk < 8; ++kk)
        #pragma unroll
        for (int m = 0; m < 2; ++m) {
            const unsigned short* wp =
                &wb[(size_t)(h * 128 + wv * 32 + m * 16 + ol) * CDIM + kk * 32 + g * 8];
            asm volatile("global_load_dwordx4 %0, %1, off"
                         : "=v"(wf[kk][m]) : "v"(wp));
        }

    // ---- staging: 28 asm loads, ALL issued before the single wait ---------
    // item space: 128 channel-pairs x 28 vec4-slots = 3584 = 14 * 256
    f32x4 r0[14], r1[14];
    #pragma unroll
    for (int i = 0; i < 14; ++i) {
        const int idx = tid + i * 256;
        const int cp  = idx / 28;                 // magic-mul
        const int pv  = idx - cp * 28;
        const int c0  = cp * 2;
        const int d   = (cp < 16) ? -1 : (cp < 32 ? 1 : 0);
        const bool valid = !((d == -1 && tf == 0) || (d == 1 && tf == 7));
        const float* s = x + ((size_t)(n + (valid ? d : 0)) * CDIM + c0) * HWPX
                           + p0 + pv * 4;
        asm volatile("global_load_dwordx4 %0, %1, off" : "=v"(r0[i]) : "v"(s));
        const float* s1 = s + HWPX;
        asm volatile("global_load_dwordx4 %0, %1, off" : "=v"(r1[i]) : "v"(s1));
    }
    asm volatile("s_waitcnt vmcnt(0)" ::: "memory");   // drains wf + staging
    __builtin_amdgcn_sched_barrier(0);

    // ---- convert + swizzled LDS write (zero-substitute invalid items) -----
    #pragma unroll
    for (int i = 0; i < 14; ++i) {
        const int idx = tid + i * 256;
        const int cp  = idx / 28;
        const int pv  = idx - cp * 28;
        const int c0  = cp * 2;
        const int d   = (cp < 16) ? -1 : (cp < 32 ? 1 : 0);
        const bool valid = !((d == -1 && tf == 0) || (d == 1 && tf == 7));
        const int cc = c0 ^ ((pv & 7) << 3);
        const int rb = pv * 4 * LROW + cc;        // cc even -> 4B aligned
        #pragma unroll
        for (int r = 0; r < 4; ++r)
            *(unsigned int*)&y[rb + r * LROW] =
                valid ? pk2(r0[i][r], r1[i][r]) : 0u;
    }
    __syncthreads();

    // ---- MFMA: D[o,p] = W[o,:] x Y[:,p] (zero global loads) ---------------
    f32x4 acc[2][7];
    #pragma unroll
    for (int m = 0; m < 2; ++m)
        #pragma unroll
        for (int nn = 0; nn < 7; ++nn)
            acc[m][nn] = f32x4{0.f, 0.f, 0.f, 0.f};

    #pragma unroll
    for (int kk = 0; kk < 8; ++kk) {
        const int c = kk * 32 + g * 8;            // k = g*8 + j for A and B
        #pragma unroll
        for (int nn = 0; nn < 7; ++nn) {
            const int p  = nn * 16 + ol;
            const int cc = c ^ (((p >> 2) & 7) << 3);
            const bf16x8 bf = *(const bf16x8*)&y[p * LROW + cc];
            acc[0][nn] = __builtin_amdgcn_mfma_f32_16x16x32_bf16(wf[kk][0], bf, acc[0][nn], 0, 0, 0);
            acc[1][nn] = __builtin_amdgcn_mfma_f32_16x16x32_bf16(wf[kk][1], bf, acc[1][nn], 0, 0, 0);
        }
    }

    // ---- epilogue: C/D col=lane&15 (pixel), row=(lane>>4)*4+r (channel) ---
    const size_t outbase = (size_t)n * CDIM * HWPX + p0 + ol;
    #pragma unroll
    for (int m = 0; m < 2; ++m) {
        #pragma unroll
        for (int r = 0; r < 4; ++r) {
            const int o = h * 128 + wv * 32 + m * 16 + g * 4 + r;
            float* orow = out + outbase + (size_t)o * HWPX;
            #pragma unroll
            for (int nn = 0; nn < 7; ++nn)
                orow[nn * 16] = acc[m][nn][r];
        }
    }
}

// ---- fallback (no workspace): R3 kernel, known-correct ---------------------
#define LDS_STRIDE 264
__global__ __launch_bounds__(512, 4)
void tsm_fallback(const float* __restrict__ x, const float* __restrict__ w,
                  float* __restrict__ out) {
    __shared__ __align__(16) unsigned short ylds[P_TILE * LDS_STRIDE];
    const int n = blockIdx.x, tile = blockIdx.y, p0 = tile * P_TILE;
    const int tid = threadIdx.x, tf = n & 7;
    f32x4 v0[7], v1[7]; int cps[7], pvs[7];
    #pragma unroll
    for (int i = 0; i < 7; ++i) {
        const int idx = tid + i * 512, cp = idx / 28, pv = idx - cp * 28;
        cps[i] = cp; pvs[i] = pv;
        const int c0 = cp * 2;
        int nsrc; bool valid;
        if (c0 < 32)      { nsrc = n - 1; valid = (tf > 0); }
        else if (c0 < 64) { nsrc = n + 1; valid = (tf < 7); }
        else              { nsrc = n;     valid = true; }
        const float* src = x + ((size_t)(valid ? nsrc : n) * CDIM + c0) * HWPX + p0 + pv * 4;
        f32x4 a = {0,0,0,0}, b = {0,0,0,0};
        if (valid) { a = *(const f32x4*)src; b = *(const f32x4*)(src + HWPX); }
        v0[i] = a; v1[i] = b;
    }
    #pragma unroll
    for (int i = 0; i < 7; ++i) {
        const int c0 = cps[i] * 2, pv = pvs[i];
        const int cc = c0 ^ ((pv & 7) << 3);
        const int rb = pv * 4 * LDS_STRIDE + cc;
        #pragma unroll
        for (int r = 0; r < 4; ++r)
            *(unsigned int*)&ylds[rb + r * LDS_STRIDE] = pk2(v0[i][r], v1[i][r]);
    }
    __syncthreads();
    const int lane = tid & 63, wv = tid >> 6, g = lane >> 4, ol = lane & 15;
    f32x4 acc[2][7];
    #pragma unroll
    for (int m = 0; m < 2; ++m)
        #pragma unroll
        for (int nn = 0; nn < 7; ++nn) acc[m][nn] = f32x4{0,0,0,0};
    #pragma unroll
    for (int kk = 0; kk < 8; ++kk) {
        const int c = kk * 32 + g * 8;
        bf16x8 af[2];
        #pragma unroll
        for (int m = 0; m < 2; ++m) {
            const float* wp = w + (size_t)(wv * 32 + m * 16 + ol) * CDIM + c;
            f32x4 w0 = *(const f32x4*)wp, w1 = *(const f32x4*)(wp + 4);
            union { bf16x8 v; unsigned int u4[4]; } cv;
            cv.u4[0] = pk2(w0[0], w0[1]); cv.u4[1] = pk2(w0[2], w0[3]);
            cv.u4[2] = pk2(w1[0], w1[1]); cv.u4[3] = pk2(w1[2], w1[3]);
            af[m] = cv.v;
        }
        #pragma unroll
        for (int nn = 0; nn < 7; ++nn) {
            const int p = nn * 16 + ol;
            const int cc = c ^ (((p >> 2) & 7) << 3);
            const bf16x8 bf = *(const bf16x8*)&ylds[p * LDS_STRIDE + cc];
            #pragma unroll
            for (int m = 0; m < 2; ++m)
                acc[m][nn] = __builtin_amdgcn_mfma_f32_16x16x32_bf16(af[m], bf, acc[m][nn], 0, 0, 0);
        }
    }
    const size_t outbase = (size_t)n * CDIM * HWPX + p0 + ol;
    #pragma unroll
    for (int m = 0; m < 2; ++m)
        #pragma unroll
        for (int r = 0; r < 4; ++r) {
            const int o = wv * 32 + m * 16 + g * 4 + r;
            float* orow = out + outbase + (size_t)o * HWPX;
            #pragma unroll
            for (int nn = 0; nn < 7; ++nn) orow[nn * 16] = acc[m][nn][r];
        }
}

extern "C" void kernel_launch(void* const* d_in, const int* in_sizes, int n_in,
                              void* d_out, int out_size, void* d_ws, size_t ws_size,
                              hipStream_t stream) {
    const float* x = (const float*)d_in[0];
    const float* w = (const float*)d_in[1];
    float* out     = (float*)d_out;
    const size_t wb_bytes = (size_t)CDIM * CDIM * sizeof(unsigned short); // 128KB
    if (ws_size >= wb_bytes) {
        unsigned short* wbuf = (unsigned short*)d_ws;
        wconv<<<64, 256, 0, stream>>>(w, wbuf);
        tsm_deep<<<NWG, 256, 0, stream>>>(x, wbuf, out);
    } else {
        tsm_fallback<<<dim3(128, 7, 1), dim3(512, 1, 1), 0, stream>>>(x, w, out);
    }
}

// Round 10
// 48.572 us; speedup vs baseline: 2.2687x; 1.0384x over previous
//
#include <hip/hip_runtime.h>
#include <hip/hip_bf16.h>

// TSM temporal shift + 1x1 conv (256->256) fused as bf16 MFMA GEMM.
// x: [128, 256, 28, 28] f32, w: [256, 256] f32, out: [128, 256, 28, 28] f32.
// out[n,o,p] = sum_c W[o,c] * Y_n[c,p],
//   Y_n[c,p] = x[n-1,c,p] (c<32, t>0), x[n+1,c,p] (32<=c<64, t<7), x[n,c,p] else.
//
// R10 = R9 + K-split pipeline + 4-bf16-granular LDS swizzle.
//  - Items i<7 are exactly channels 0..127 (static prefix). Issue all 28
//    loads; vmcnt(14) -> write c<128 half -> sync -> MFMA kk0..3 WHILE the
//    c>=128 loads fly -> vmcnt(0) -> write half2 (disjoint columns) -> sync
//    -> MFMA kk4..7 (same accumulators). Compute hides half2 latency.
//  - Swizzle h(p) = ((p>>3)&7)<<2 touches bank bits 1-3: writes <=2-way
//    (free), reads as two ds_read_b64 at e0 and e0^4 (uniform 4/bank).
//    Element map: Y[c+j] at (c^h)^(4*(jh^z0)) -> lo half always at c^h,
//    hi half always at (c^h)^4.

#define CDIM 256
#define HWPX 784
#define FRST (CDIM * HWPX)        // 200704 floats per frame
#define P_TILE 112
#define NPT  7                    // 112-px tiles per frame
#define NWG  (128 * NPT * 2)      // 1792 blocks (x2 o-halves), % 8 == 0
#define LROW 264                  // bf16 per LDS pixel row (528 B)

using bf16x8 = __attribute__((ext_vector_type(8))) short;
using bf16x4 = __attribute__((ext_vector_type(4))) short;
using f32x4  = __attribute__((ext_vector_type(4))) float;

static __device__ __forceinline__ unsigned int pk2(float lo, float hi) {
    union { __hip_bfloat162 h; unsigned int u; } cv;
    cv.h = __float22bfloat162_rn(make_float2(lo, hi));
    return cv.u;
}

// ---- W f32 -> bf16 row-major (one-shot) ------------------------------------
__global__ void wconv(const float* __restrict__ w, unsigned short* __restrict__ wb) {
    const int i = (blockIdx.x * 256 + threadIdx.x) * 4;
    f32x4 v = *(const f32x4*)(w + i);
    *(uint2*)(wb + i) = make_uint2(pk2(v[0], v[1]), pk2(v[2], v[3]));
}

__global__ __launch_bounds__(256, 2)   // 256-reg budget, 2 blocks/CU (LDS-capped)
void tsm_ksplit(const float* __restrict__ x,
                const unsigned short* __restrict__ wb,
                float* __restrict__ out) {
    __shared__ __align__(16) unsigned short y[P_TILE * LROW];   // 59136 B

    const int bid = blockIdx.x;
    const int wg  = (bid & 7) * (NWG / 8) + (bid >> 3);   // XCD-bijective
    const int h    = wg & 1;              // o-half
    const int pair = wg >> 1;
    const int n    = pair / NPT;          // frame
    const int pt   = pair - n * NPT;
    const int p0   = pt * P_TILE;
    const int tid  = threadIdx.x;
    const int tf   = n & 7;

    const int lane = tid & 63;
    const int wv   = tid >> 6;
    const int g    = lane >> 4;
    const int ol   = lane & 15;

    // ---- W panel (asm-pinned once; drained at the first vmcnt) ------------
    bf16x8 wf[8][2];
    #pragma unroll
    for (int kk = 0; kk < 8; ++kk)
        #pragma unroll
        for (int m = 0; m < 2; ++m) {
            const unsigned short* wp =
                &wb[(size_t)(h * 128 + wv * 32 + m * 16 + ol) * CDIM + kk * 32 + g * 8];
            asm volatile("global_load_dwordx4 %0, %1, off"
                         : "=v"(wf[kk][m]) : "v"(wp));
        }

    // ---- staging: all 28 loads issued; items i<7 == channels 0..127 -------
    f32x4 r0[14], r1[14];
    #pragma unroll
    for (int i = 0; i < 14; ++i) {
        const int idx = tid + i * 256;
        const int cp  = idx / 28;                 // magic-mul
        const int pv  = idx - cp * 28;
        const int c0  = cp * 2;
        const int d   = (cp < 16) ? -1 : (cp < 32 ? 1 : 0);
        const bool valid = !((d == -1 && tf == 0) || (d == 1 && tf == 7));
        const float* s = x + ((size_t)(n + (valid ? d : 0)) * CDIM + c0) * HWPX
                           + p0 + pv * 4;
        asm volatile("global_load_dwordx4 %0, %1, off" : "=v"(r0[i]) : "v"(s));
        const float* s1 = s + HWPX;
        asm volatile("global_load_dwordx4 %0, %1, off" : "=v"(r1[i]) : "v"(s1));
    }

    #define WRITE_ITEM(i)                                                      \
    {                                                                          \
        const int idx = tid + (i) * 256;                                       \
        const int cp  = idx / 28;                                              \
        const int pv  = idx - cp * 28;                                         \
        const int c0  = cp * 2;                                                \
        const int d   = (cp < 16) ? -1 : (cp < 32 ? 1 : 0);                    \
        const bool valid = !((d == -1 && tf == 0) || (d == 1 && tf == 7));     \
        const int cc  = c0 ^ (((pv >> 1) & 7) << 2);  /* h(p), p=pv*4+r */     \
        const int rb  = pv * 4 * LROW + cc;                                    \
        _Pragma("unroll")                                                      \
        for (int r = 0; r < 4; ++r)                                            \
            *(unsigned int*)&y[rb + r * LROW] =                                \
                valid ? pk2(r0[i][r], r1[i][r]) : 0u;                          \
    }

    // wait wf(16) + first 14 loads; newest 14 (c>=128) stay in flight
    asm volatile("s_waitcnt vmcnt(14)" ::: "memory");
    __builtin_amdgcn_sched_barrier(0);
    #pragma unroll
    for (int i = 0; i < 7; ++i) WRITE_ITEM(i)
    __syncthreads();

    f32x4 acc[2][7];
    #pragma unroll
    for (int m = 0; m < 2; ++m)
        #pragma unroll
        for (int nn = 0; nn < 7; ++nn)
            acc[m][nn] = f32x4{0.f, 0.f, 0.f, 0.f};

    #define COMPUTE(K0, K1)                                                    \
    {                                                                          \
        _Pragma("unroll")                                                      \
        for (int nn = 0; nn < 7; ++nn) {                                       \
            const int p    = nn * 16 + ol;                                     \
            const int zz   = ((p >> 3) & 7) << 2;                              \
            const int rowb = p * LROW;                                         \
            _Pragma("unroll")                                                  \
            for (int kk = (K0); kk < (K1); ++kk) {                             \
                const int c  = kk * 32 + g * 8;                                \
                const int e0 = c ^ zz;                                         \
                const bf16x4 lo = *(const bf16x4*)&y[rowb + e0];               \
                const bf16x4 hi = *(const bf16x4*)&y[rowb + (e0 ^ 4)];         \
                const bf16x8 bf = __builtin_shufflevector(lo, hi,              \
                                                          0, 1, 2, 3, 4, 5, 6, 7); \
                acc[0][nn] = __builtin_amdgcn_mfma_f32_16x16x32_bf16(          \
                    wf[kk][0], bf, acc[0][nn], 0, 0, 0);                       \
                acc[1][nn] = __builtin_amdgcn_mfma_f32_16x16x32_bf16(          \
                    wf[kk][1], bf, acc[1][nn], 0, 0, 0);                       \
            }                                                                  \
        }                                                                      \
    }

    // ---- pass 1: kk 0..3 (columns < 128) while half-2 loads fly -----------
    COMPUTE(0, 4)

    // ---- half 2 arrives; write columns 128..255 (disjoint, no read race) --
    asm volatile("s_waitcnt vmcnt(0)" ::: "memory");
    __builtin_amdgcn_sched_barrier(0);
    #pragma unroll
    for (int i = 7; i < 14; ++i) WRITE_ITEM(i)
    __syncthreads();

    // ---- pass 2: kk 4..7, accumulate into same acc ------------------------
    COMPUTE(4, 8)

    // ---- epilogue: C/D col=lane&15 (pixel), row=(lane>>4)*4+r (channel) ---
    const size_t outbase = (size_t)n * CDIM * HWPX + p0 + ol;
    #pragma unroll
    for (int m = 0; m < 2; ++m) {
        #pragma unroll
        for (int r = 0; r < 4; ++r) {
            const int o = h * 128 + wv * 32 + m * 16 + g * 4 + r;
            float* orow = out + outbase + (size_t)o * HWPX;
            #pragma unroll
            for (int nn = 0; nn < 7; ++nn)
                orow[nn * 16] = acc[m][nn][r];
        }
    }
    #undef WRITE_ITEM
    #undef COMPUTE
}

// ---- fallback (no workspace): R3 kernel, known-correct ---------------------
#define LDS_STRIDE 264
__global__ __launch_bounds__(512, 4)
void tsm_fallback(const float* __restrict__ x, const float* __restrict__ w,
                  float* __restrict__ out) {
    __shared__ __align__(16) unsigned short ylds[P_TILE * LDS_STRIDE];
    const int n = blockIdx.x, tile = blockIdx.y, p0 = tile * P_TILE;
    const int tid = threadIdx.x, tf = n & 7;
    f32x4 v0[7], v1[7]; int cps[7], pvs[7];
    #pragma unroll
    for (int i = 0; i < 7; ++i) {
        const int idx = tid + i * 512, cp = idx / 28, pv = idx - cp * 28;
        cps[i] = cp; pvs[i] = pv;
        const int c0 = cp * 2;
        int nsrc; bool valid;
        if (c0 < 32)      { nsrc = n - 1; valid = (tf > 0); }
        else if (c0 < 64) { nsrc = n + 1; valid = (tf < 7); }
        else              { nsrc = n;     valid = true; }
        const float* src = x + ((size_t)(valid ? nsrc : n) * CDIM + c0) * HWPX + p0 + pv * 4;
        f32x4 a = {0,0,0,0}, b = {0,0,0,0};
        if (valid) { a = *(const f32x4*)src; b = *(const f32x4*)(src + HWPX); }
        v0[i] = a; v1[i] = b;
    }
    #pragma unroll
    for (int i = 0; i < 7; ++i) {
        const int c0 = cps[i] * 2, pv = pvs[i];
        const int cc = c0 ^ ((pv & 7) << 3);
        const int rb = pv * 4 * LDS_STRIDE + cc;
        #pragma unroll
        for (int r = 0; r < 4; ++r)
            *(unsigned int*)&ylds[rb + r * LDS_STRIDE] = pk2(v0[i][r], v1[i][r]);
    }
    __syncthreads();
    const int lane = tid & 63, wv = tid >> 6, g = lane >> 4, ol = lane & 15;
    f32x4 acc[2][7];
    #pragma unroll
    for (int m = 0; m < 2; ++m)
        #pragma unroll
        for (int nn = 0; nn < 7; ++nn) acc[m][nn] = f32x4{0,0,0,0};
    #pragma unroll
    for (int kk = 0; kk < 8; ++kk) {
        const int c = kk * 32 + g * 8;
        bf16x8 af[2];
        #pragma unroll
        for (int m = 0; m < 2; ++m) {
            const float* wp = w + (size_t)(wv * 32 + m * 16 + ol) * CDIM + c;
            f32x4 w0 = *(const f32x4*)wp, w1 = *(const f32x4*)(wp + 4);
            union { bf16x8 v; unsigned int u4[4]; } cv;
            cv.u4[0] = pk2(w0[0], w0[1]); cv.u4[1] = pk2(w0[2], w0[3]);
            cv.u4[2] = pk2(w1[0], w1[1]); cv.u4[3] = pk2(w1[2], w1[3]);
            af[m] = cv.v;
        }
        #pragma unroll
        for (int nn = 0; nn < 7; ++nn) {
            const int p = nn * 16 + ol;
            const int cc = c ^ (((p >> 2) & 7) << 3);
            const bf16x8 bf = *(const bf16x8*)&ylds[p * LDS_STRIDE + cc];
            #pragma unroll
            for (int m = 0; m < 2; ++m)
                acc[m][nn] = __builtin_amdgcn_mfma_f32_16x16x32_bf16(af[m], bf, acc[m][nn], 0, 0, 0);
        }
    }
    const size_t outbase = (size_t)n * CDIM * HWPX + p0 + ol;
    #pragma unroll
    for (int m = 0; m < 2; ++m)
        #pragma unroll
        for (int r = 0; r < 4; ++r) {
            const int o = wv * 32 + m * 16 + g * 4 + r;
            float* orow = out + outbase + (size_t)o * HWPX;
            #pragma unroll
            for (int nn = 0; nn < 7; ++nn) orow[nn * 16] = acc[m][nn][r];
        }
}

extern "C" void kernel_launch(void* const* d_in, const int* in_sizes, int n_in,
                              void* d_out, int out_size, void* d_ws, size_t ws_size,
                              hipStream_t stream) {
    const float* x = (const float*)d_in[0];
    const float* w = (const float*)d_in[1];
    float* out     = (float*)d_out;
    const size_t wb_bytes = (size_t)CDIM * CDIM * sizeof(unsigned short); // 128KB
    if (ws_size >= wb_bytes) {
        unsigned short* wbuf = (unsigned short*)d_ws;
        wconv<<<64, 256, 0, stream>>>(w, wbuf);
        tsm_ksplit<<<NWG, 256, 0, stream>>>(x, wbuf, out);
    } else {
        tsm_fallback<<<dim3(128, 7, 1), dim3(512, 1, 1), 0, stream>>>(x, w, out);
    }
}